// Round 1
// baseline (4985.217 us; speedup 1.0000x reference)
//
#include <hip/hip_runtime.h>
#include <stdint.h>
#include <stddef.h>

// Problem dims
#define B_  128
#define S_  48
#define E_  620
#define EP  640    // E padded to multiple of 32 (zeros)
#define H_  2400
#define N3  7200   // 3*H (r,i,n concatenated)
#define KH  2400
#define ZSPLIT 5     // phase-2 k-split: 5 chunks x 480 (15 iters of 32)
#define P2_ITERS 15
#define P1_ITERS 20  // phase-1 K = 640 = 20 x 32
#define NTILES 225   // N3 / 32  (phase-2 n-tiles)
#define GGRP   75    // H_ / 32  (gate j-groups; 15 contributor blocks each)
#define CNT_STRIDE 32  // pad counters to separate cache lines

typedef _Float16 half_t;
typedef __attribute__((ext_vector_type(8))) _Float16 half8;
typedef __attribute__((ext_vector_type(4))) _Float16 half4;
typedef __attribute__((ext_vector_type(4))) float    floatx4;

// Workgroup barrier that waits ONLY on LDS ops; in-flight global loads keep
// flying. 0xC07F = vmcnt(63) expcnt(7) lgkmcnt(0).  (phase-1 only)
__device__ __forceinline__ void lds_barrier() {
  __builtin_amdgcn_sched_barrier(0);
  __builtin_amdgcn_s_waitcnt(0xC07F);
  __builtin_amdgcn_s_barrier();
  __builtin_amdgcn_sched_barrier(0);
}

// ---- x = fp16(emb[tokens]), padded [6144, 640] ----
__global__ void gather_cast_x(const int* __restrict__ tokens,
                              const float* __restrict__ emb,
                              half_t* __restrict__ xb) {
  int idx = blockIdx.x * 256 + threadIdx.x;       // over 6144*EP
  int m = idx / EP, c = idx - m * EP;
  float v = 0.f;
  if (c < E_) v = emb[(size_t)tokens[m] * E_ + c];
  xb[idx] = (half_t)v;
}

// ---- W_i = fp16 concat(W_ir,W_ii,W_in) [7200, 640]; bias concat [7200] ----
__global__ void convert_wi(const float* __restrict__ Wir, const float* __restrict__ Wii,
                           const float* __restrict__ Win,
                           const float* __restrict__ bir, const float* __restrict__ bii,
                           const float* __restrict__ bin,
                           half_t* __restrict__ Wi, float* __restrict__ bias) {
  int idx = blockIdx.x * 256 + threadIdx.x;       // over N3*EP
  int r = idx / EP, c = idx - r * EP;
  const float* W = (r < H_) ? Wir : (r < 2*H_ ? Wii : Win);
  int rr = (r < H_) ? r : (r < 2*H_ ? r - H_ : r - 2*H_);
  float v = (c < E_) ? W[(size_t)rr * E_ + c] : 0.f;
  Wi[idx] = (half_t)v;
  if (c == 0) {
    const float* bb = (r < H_) ? bir : (r < 2*H_ ? bii : bin);
    bias[r] = bb[rr];
  }
}

// ---- Wf = fp16 concat(W_hr,W_hi,W_hn) [7200, 2400] ----
__global__ void convert_wh(const float* __restrict__ Whr, const float* __restrict__ Whi,
                           const float* __restrict__ Whn, half_t* __restrict__ Wf) {
  int idx = blockIdx.x * 256 + threadIdx.x;       // over N3*KH
  int r = idx / KH, c = idx - r * KH;
  const float* W = (r < H_) ? Whr : (r < 2*H_ ? Whi : Whn);
  int rr = (r < H_) ? r : (r < 2*H_ ? r - H_ : r - 2*H_);
  Wf[idx] = (half_t)W[(size_t)rr * KH + c];
}

__global__ void init_h(float* __restrict__ h, half_t* __restrict__ hh,
                       int* __restrict__ cnt) {
  int idx = blockIdx.x * 256 + threadIdx.x;       // over B_*H_
  h[idx] = 0.f;
  hh[idx] = (half_t)0.f;
  if (idx < GGRP * CNT_STRIDE) cnt[idx] = 0;
}

// ---- Phase 1: gx = fp16( xb @ Wi^T + bias )  [6144 x 7200], K=640 ----
// (r5/r6 structure: 128x128 tile, frag-major LDS dbuf, lgkm-only barrier.)
__global__ __launch_bounds__(256, 2) void gemm_x(
    const half_t* __restrict__ A,   // xb [6144 x 640]
    const half_t* __restrict__ Bm,  // Wi [7200 x 640]
    half_t* __restrict__ C,         // gx [6144 x 7200]
    const float* __restrict__ bias)
{
  __shared__ half_t As[2][4096];
  __shared__ half_t Bs[2][4096];

  const int tid = threadIdx.x;
  const int lane = tid & 63;
  const int w = tid >> 6;
  const int m0 = blockIdx.x * 128;
  const int n0 = blockIdx.y * 128;
  const int wm = (w >> 1) * 64, wn = (w & 1) * 64;

  const int c0 = tid, c1 = tid + 256;
  const int rA0 = m0 + (c0 >> 6) * 16 + (c0 & 15), q0 = ((c0 >> 4) & 3) * 8;
  const int rA1 = m0 + (c1 >> 6) * 16 + (c1 & 15), q1 = ((c1 >> 4) & 3) * 8;
  int rB0 = n0 + (c0 >> 6) * 16 + (c0 & 15); if (rB0 >= N3) rB0 = N3 - 1;
  int rB1 = n0 + (c1 >> 6) * 16 + (c1 & 15); if (rB1 >= N3) rB1 = N3 - 1;
  const half_t* pA0 = A  + (size_t)rA0 * EP + q0;
  const half_t* pA1 = A  + (size_t)rA1 * EP + q1;
  const half_t* pB0 = Bm + (size_t)rB0 * EP + q0;
  const half_t* pB1 = Bm + (size_t)rB1 * EP + q1;

  floatx4 acc[4][4] = {};

  half8 ga0 = *(const half8*)(pA0);
  half8 ga1 = *(const half8*)(pA1);
  half8 gb0 = *(const half8*)(pB0);
  half8 gb1 = *(const half8*)(pB1);
  *(half8*)(As[0] + c0 * 8) = ga0;
  *(half8*)(As[0] + c1 * 8) = ga1;
  *(half8*)(Bs[0] + c0 * 8) = gb0;
  *(half8*)(Bs[0] + c1 * 8) = gb1;
  ga0 = *(const half8*)(pA0 + 32);
  ga1 = *(const half8*)(pA1 + 32);
  gb0 = *(const half8*)(pB0 + 32);
  gb1 = *(const half8*)(pB1 + 32);
  lds_barrier();

  #pragma unroll
  for (int i = 0; i < P1_ITERS; ++i) {
    const int cur = i & 1, nxt = cur ^ 1;
    half8 a[4], b[4];
    #pragma unroll
    for (int f = 0; f < 4; ++f) {
      a[f] = *(const half8*)(As[cur] + (((wm >> 4) + f) * 64 + lane) * 8);
      b[f] = *(const half8*)(Bs[cur] + (((wn >> 4) + f) * 64 + lane) * 8);
    }
    if (i + 1 < P1_ITERS) {
      *(half8*)(As[nxt] + c0 * 8) = ga0;
      *(half8*)(As[nxt] + c1 * 8) = ga1;
      *(half8*)(Bs[nxt] + c0 * 8) = gb0;
      *(half8*)(Bs[nxt] + c1 * 8) = gb1;
    }
    if (i + 2 < P1_ITERS) {
      int ko = (i + 2) * 32;
      ga0 = *(const half8*)(pA0 + ko);
      ga1 = *(const half8*)(pA1 + ko);
      gb0 = *(const half8*)(pB0 + ko);
      gb1 = *(const half8*)(pB1 + ko);
    }
    #pragma unroll
    for (int mf = 0; mf < 4; ++mf)
      #pragma unroll
      for (int nf = 0; nf < 4; ++nf)
        acc[mf][nf] = __builtin_amdgcn_mfma_f32_16x16x32_f16(
            a[mf], b[nf], acc[mf][nf], 0, 0, 0);
    if (i + 1 < P1_ITERS) lds_barrier();
  }

  const int col = lane & 15, qr = (lane >> 4) * 4;
  #pragma unroll
  for (int nf = 0; nf < 4; ++nf) {
    int n = n0 + wn + nf * 16 + col;
    if (n >= N3) continue;
    float bv = bias[n];
    #pragma unroll
    for (int mf = 0; mf < 4; ++mf)
      #pragma unroll
      for (int r = 0; r < 4; ++r)
        __builtin_nontemporal_store(
            (half_t)(acc[mf][nf][r] + bv),
            &C[(size_t)(m0 + wm + mf * 16 + qr + r) * N3 + n]);
  }
}

// ---- Phase 2 FUSED: Gp[z] = hh(128 x 480-chunk) @ Wf^T  +  gate update.
// n-tile 32 (grid 225 x 5 = 1125 blocks, 4.4/CU), LDS-free, barrier-free
// main loop; B-ring depth 5, A-ring depth 2. After writing its Gp partial,
// each block bumps cnt[g] (g = n_tile % 75); the 15th (last) contributor of
// a j-group does the gate math for its 32 hidden columns directly from
// cache-hot Gp — eliminating the separate gate_step kernel (48 launches)
// and its cold Gp re-read. No spinning: safe under any block scheduling.
// h/hh are ping-ponged across steps (old read, new written) so late gemm
// blocks never race the finishers' h writes.
__global__ __launch_bounds__(256, 4) void gemm_gate(
    const half_t* __restrict__ Ah,    // hh_old [128 x 2400]
    const half_t* __restrict__ Wf,    // [7200 x 2400]
    float* __restrict__ Gp,           // [ZSPLIT][128][7200] scratch
    const half_t* __restrict__ gx,    // [6144 x 7200]
    const float* __restrict__ hold,   // h_old  [128 x 2400] fp32
    float* __restrict__ hnew,         // h_new
    half_t* __restrict__ hhnew,       // hh_new
    const int* __restrict__ lengths,
    float* __restrict__ out,
    int* __restrict__ cnt,            // [GGRP*CNT_STRIDE]
    int t)
{
  const int tid  = threadIdx.x;
  const int lane = tid & 63;
  const int w    = tid >> 6;
  const int ntile = blockIdx.x;        // 0..224
  const int z     = blockIdx.y;        // 0..4
  const int n0 = ntile * 32;
  const int kb = z * 480;
  const int wm = w * 32;               // wave m-offset (4 waves stack m)

  const int fm = lane & 15;            // frag row within 16
  const int fk = (lane >> 4) * 8;      // frag k-offset

  const half_t* pA0 = Ah + (size_t)(wm + fm) * KH + kb + fk;
  const half_t* pA1 = pA0 + 16 * (size_t)KH;
  const half_t* pB0 = Wf + (size_t)(n0 + fm) * KH + kb + fk;
  const half_t* pB1 = pB0 + 16 * (size_t)KH;

  floatx4 acc[2][2] = {};   // 16 VGPR

  half8 aR[2][2];           // A ring, depth 2 (hh is L2-hot)
  half8 bR[5][2];           // B ring, depth 5 (Wf L2/L3 latency cover)
  #pragma unroll
  for (int d = 0; d < 2; ++d) {
    aR[d][0] = *(const half8*)(pA0 + d * 32);
    aR[d][1] = *(const half8*)(pA1 + d * 32);
  }
  #pragma unroll
  for (int d = 0; d < 5; ++d) {
    bR[d][0] = *(const half8*)(pB0 + d * 32);
    bR[d][1] = *(const half8*)(pB1 + d * 32);
  }

  #pragma unroll
  for (int i = 0; i < P2_ITERS; ++i) {
    half8 a0 = aR[i & 1][0], a1 = aR[i & 1][1];
    half8 b0 = bR[i % 5][0], b1 = bR[i % 5][1];
    if (i + 2 < P2_ITERS) {
      int ko = (i + 2) * 32;
      aR[i & 1][0] = *(const half8*)(pA0 + ko);
      aR[i & 1][1] = *(const half8*)(pA1 + ko);
    }
    if (i + 5 < P2_ITERS) {
      int ko = (i + 5) * 32;
      bR[i % 5][0] = *(const half8*)(pB0 + ko);
      bR[i % 5][1] = *(const half8*)(pB1 + ko);
    }
    acc[0][0] = __builtin_amdgcn_mfma_f32_16x16x32_f16(a0, b0, acc[0][0], 0, 0, 0);
    acc[1][0] = __builtin_amdgcn_mfma_f32_16x16x32_f16(a1, b0, acc[1][0], 0, 0, 0);
    acc[0][1] = __builtin_amdgcn_mfma_f32_16x16x32_f16(a0, b1, acc[0][1], 0, 0, 0);
    acc[1][1] = __builtin_amdgcn_mfma_f32_16x16x32_f16(a1, b1, acc[1][1], 0, 0, 0);
  }

  // Partial-sum epilogue: nontemporal (write-once, read-once dead data —
  // keep it from evicting the per-XCD Wf slice out of L2).
  const int col = lane & 15, qr = (lane >> 4) * 4;
  float* G = Gp + (size_t)z * (B_ * N3);
  #pragma unroll
  for (int nf = 0; nf < 2; ++nf) {
    int n = n0 + nf * 16 + col;
    #pragma unroll
    for (int mf = 0; mf < 2; ++mf)
      #pragma unroll
      for (int r = 0; r < 4; ++r)
        __builtin_nontemporal_store(
            acc[mf][nf][r],
            &G[(size_t)(wm + mf * 16 + qr + r) * N3 + n]);
  }

  // ---- last-contributor gate fusion ----
  __shared__ int isLast;
  __syncthreads();                       // drains all threads' stores (vmcnt 0)
  const int g = ntile % GGRP;
  if (tid == 0) {
    __threadfence();                     // release: L2 -> device coherence point
    isLast = (atomicAdd(&cnt[g * CNT_STRIDE], 1) == 14);
  }
  __syncthreads();
  if (!isLast) return;
  __threadfence();                       // acquire: invalidate stale cache lines

  const int j0 = g * 32;
  #pragma unroll
  for (int pass = 0; pass < 4; ++pass) {
    int b = pass * 32 + (tid >> 3);      // 0..127
    int j = j0 + (tid & 7) * 4;          // 4 consecutive hidden cols
    size_t gb = (size_t)b * N3;
    floatx4 Gr = {}, Gi = {}, Gn = {};
    #pragma unroll
    for (int zz = 0; zz < ZSPLIT; ++zz) {
      const float* base = Gp + (size_t)zz * (B_ * N3) + gb;
      Gr += __builtin_nontemporal_load((const floatx4*)(base + j));
      Gi += __builtin_nontemporal_load((const floatx4*)(base + H_ + j));
      Gn += __builtin_nontemporal_load((const floatx4*)(base + 2 * H_ + j));
    }
    size_t rx = ((size_t)b * S_ + t) * N3;
    half4 hxr = *(const half4*)(gx + rx + j);
    half4 hxi = *(const half4*)(gx + rx + H_ + j);
    half4 hxn = *(const half4*)(gx + rx + 2 * H_ + j);
    floatx4 ho = *(const floatx4*)(hold + (size_t)b * H_ + j);
    int lc = lengths[b] - 1;
    lc = lc < 0 ? 0 : (lc > S_ - 1 ? S_ - 1 : lc);

    floatx4 hn_;
    half4 hh4;
    #pragma unroll
    for (int e = 0; e < 4; ++e) {
      float r  = 1.f / (1.f + __expf(-((float)hxr[e] + Gr[e])));
      float ig = 1.f / (1.f + __expf(-((float)hxi[e] + Gi[e])));
      float nn = tanhf((float)hxn[e] + r * Gn[e]);
      hn_[e] = (1.f - ig) * nn + ig * ho[e];
      hh4[e] = (half_t)hn_[e];
    }
    *(floatx4*)(hnew  + (size_t)b * H_ + j) = hn_;
    *(half4*) (hhnew + (size_t)b * H_ + j) = hh4;
    if (t == lc) *(floatx4*)(out + (size_t)b * H_ + j) = hn_;
  }
  if (tid == 0) cnt[g * CNT_STRIDE] = 0;   // re-arm for the next step's kernel
}

extern "C" void kernel_launch(void* const* d_in, const int* in_sizes, int n_in,
                              void* d_out, int out_size, void* d_ws, size_t ws_size,
                              hipStream_t stream)
{
  const int*   tokens  = (const int*)d_in[0];
  const int*   lengths = (const int*)d_in[1];
  const float* emb = (const float*)d_in[2];
  const float* Wir = (const float*)d_in[3];
  const float* Wii = (const float*)d_in[4];
  const float* Win = (const float*)d_in[5];
  const float* bir = (const float*)d_in[6];
  const float* bii = (const float*)d_in[7];
  const float* bin = (const float*)d_in[8];
  const float* Whr = (const float*)d_in[9];
  const float* Whi = (const float*)d_in[10];
  const float* Whn = (const float*)d_in[11];
  float* out = (float*)d_out;

  char* ws = (char*)d_ws;
  size_t off = 0;
  auto alloc = [&](size_t bytes) {
    void* p = ws + off;
    off = (off + bytes + 255) & ~(size_t)255;
    return p;
  };
  half_t* xb   = (half_t*)alloc((size_t)(B_ * S_) * EP * 2);   //  7.9 MB
  half_t* Wi   = (half_t*)alloc((size_t)N3 * EP * 2);          //  9.2 MB
  half_t* Wf   = (half_t*)alloc((size_t)N3 * KH * 2);          // 34.6 MB
  float*  bias = (float*)alloc((size_t)N3 * 4);
  half_t* gx   = (half_t*)alloc((size_t)(B_ * S_) * N3 * 2);   // 88.5 MB
  float*  Gp   = (float*)alloc((size_t)ZSPLIT * B_ * N3 * 4);  // 18.4 MB
  float*  h0   = (float*)alloc((size_t)B_ * H_ * 4);           // ping-pong h
  float*  h1   = (float*)alloc((size_t)B_ * H_ * 4);
  half_t* hh0  = (half_t*)alloc((size_t)B_ * H_ * 2);
  half_t* hh1  = (half_t*)alloc((size_t)B_ * H_ * 2);
  int*    cnt  = (int*)alloc((size_t)GGRP * CNT_STRIDE * 4);

  gather_cast_x<<<(B_ * S_ * EP) / 256, 256, 0, stream>>>(tokens, emb, xb);
  convert_wi<<<(N3 * EP) / 256, 256, 0, stream>>>(Wir, Wii, Win, bir, bii, bin, Wi, bias);
  convert_wh<<<(N3 * KH) / 256, 256, 0, stream>>>(Whr, Whi, Whn, Wf);
  init_h<<<(B_ * H_) / 256, 256, 0, stream>>>(h0, hh0, cnt);

  // Phase 1: gates_x = fp16( x @ W_i^T + b )   [6144 x 7200]
  gemm_x<<<dim3(48, 57), 256, 0, stream>>>(xb, Wi, gx, bias);

  // Phase 2: 48 sequential fused GRU steps (1 dispatch/step, ping-pong state)
  for (int t = 0; t < S_; ++t) {
    const half_t* hi = (t & 1) ? hh1 : hh0;
    half_t*       hw = (t & 1) ? hh0 : hh1;
    const float*  ho = (t & 1) ? h1  : h0;
    float*        hn = (t & 1) ? h0  : h1;
    gemm_gate<<<dim3(NTILES, ZSPLIT), 256, 0, stream>>>(
        hi, Wf, Gp, gx, ho, hn, hw, lengths, out, cnt, t);
  }
}

// Round 4
// 2169.118 us; speedup vs baseline: 2.2983x; 2.2983x over previous
//
#include <hip/hip_runtime.h>
#include <stdint.h>
#include <stddef.h>

// Problem dims
#define B_  128
#define S_  48
#define E_  620
#define EP  640    // E padded to multiple of 32 (zeros)
#define H_  2400
#define N3  7200   // 3*H (r,i,n concatenated)
#define KH  2400
#define P1_ITERS 20  // phase-1 K = 640 = 20 x 32
#define P2_ITERS 75  // phase-2 K = 2400 = 75 x 32 (full K, no split)
#define RING 5       // ring depth for A and B (75 % 5 == 0)
#define GBLK 150     // H_/16 hidden-unit groups = grid of phase 2

typedef _Float16 half_t;
typedef __attribute__((ext_vector_type(8))) _Float16 half8;
typedef __attribute__((ext_vector_type(4))) float    floatx4;

// Workgroup barrier that waits ONLY on LDS ops; in-flight global loads keep
// flying. 0xC07F = vmcnt(63) expcnt(7) lgkmcnt(0).  (phase-1 only)
__device__ __forceinline__ void lds_barrier() {
  __builtin_amdgcn_sched_barrier(0);
  __builtin_amdgcn_s_waitcnt(0xC07F);
  __builtin_amdgcn_s_barrier();
  __builtin_amdgcn_sched_barrier(0);
}

// ---- x = fp16(emb[tokens]), padded [6144, 640] ----
__global__ void gather_cast_x(const int* __restrict__ tokens,
                              const float* __restrict__ emb,
                              half_t* __restrict__ xb) {
  int idx = blockIdx.x * 256 + threadIdx.x;       // over 6144*EP
  int m = idx / EP, c = idx - m * EP;
  float v = 0.f;
  if (c < E_) v = emb[(size_t)tokens[m] * E_ + c];
  xb[idx] = (half_t)v;
}

// ---- W_i = fp16 concat(W_ir,W_ii,W_in) [7200, 640]; bias concat [7200] ----
__global__ void convert_wi(const float* __restrict__ Wir, const float* __restrict__ Wii,
                           const float* __restrict__ Win,
                           const float* __restrict__ bir, const float* __restrict__ bii,
                           const float* __restrict__ bin,
                           half_t* __restrict__ Wi, float* __restrict__ bias) {
  int idx = blockIdx.x * 256 + threadIdx.x;       // over N3*EP
  int r = idx / EP, c = idx - r * EP;
  const float* W = (r < H_) ? Wir : (r < 2*H_ ? Wii : Win);
  int rr = (r < H_) ? r : (r < 2*H_ ? r - H_ : r - 2*H_);
  float v = (c < E_) ? W[(size_t)rr * E_ + c] : 0.f;
  Wi[idx] = (half_t)v;
  if (c == 0) {
    const float* bb = (r < H_) ? bir : (r < 2*H_ ? bii : bin);
    bias[r] = bb[rr];
  }
}

// ---- Wf = fp16 concat(W_hr,W_hi,W_hn) [7200, 2400] ----
__global__ void convert_wh(const float* __restrict__ Whr, const float* __restrict__ Whi,
                           const float* __restrict__ Whn, half_t* __restrict__ Wf) {
  int idx = blockIdx.x * 256 + threadIdx.x;       // over N3*KH
  int r = idx / KH, c = idx - r * KH;
  const float* W = (r < H_) ? Whr : (r < 2*H_ ? Whi : Whn);
  int rr = (r < H_) ? r : (r < 2*H_ ? r - H_ : r - 2*H_);
  Wf[idx] = (half_t)W[(size_t)rr * KH + c];
}

__global__ void init_h(float* __restrict__ h, half_t* __restrict__ hh) {
  int idx = blockIdx.x * 256 + threadIdx.x;       // over B_*H_
  h[idx] = 0.f;
  hh[idx] = (half_t)0.f;
}

// ---- Phase 1: gx = fp16( xb @ Wi^T + bias )  [6144 x 7200], K=640 ----
// (r5/r6 structure: 128x128 tile, frag-major LDS dbuf, lgkm-only barrier.)
__global__ __launch_bounds__(256, 2) void gemm_x(
    const half_t* __restrict__ A,   // xb [6144 x 640]
    const half_t* __restrict__ Bm,  // Wi [7200 x 640]
    half_t* __restrict__ C,         // gx [6144 x 7200]
    const float* __restrict__ bias)
{
  __shared__ half_t As[2][4096];
  __shared__ half_t Bs[2][4096];

  const int tid = threadIdx.x;
  const int lane = tid & 63;
  const int w = tid >> 6;
  const int m0 = blockIdx.x * 128;
  const int n0 = blockIdx.y * 128;
  const int wm = (w >> 1) * 64, wn = (w & 1) * 64;

  const int c0 = tid, c1 = tid + 256;
  const int rA0 = m0 + (c0 >> 6) * 16 + (c0 & 15), q0 = ((c0 >> 4) & 3) * 8;
  const int rA1 = m0 + (c1 >> 6) * 16 + (c1 & 15), q1 = ((c1 >> 4) & 3) * 8;
  int rB0 = n0 + (c0 >> 6) * 16 + (c0 & 15); if (rB0 >= N3) rB0 = N3 - 1;
  int rB1 = n0 + (c1 >> 6) * 16 + (c1 & 15); if (rB1 >= N3) rB1 = N3 - 1;
  const half_t* pA0 = A  + (size_t)rA0 * EP + q0;
  const half_t* pA1 = A  + (size_t)rA1 * EP + q1;
  const half_t* pB0 = Bm + (size_t)rB0 * EP + q0;
  const half_t* pB1 = Bm + (size_t)rB1 * EP + q1;

  floatx4 acc[4][4] = {};

  half8 ga0 = *(const half8*)(pA0);
  half8 ga1 = *(const half8*)(pA1);
  half8 gb0 = *(const half8*)(pB0);
  half8 gb1 = *(const half8*)(pB1);
  *(half8*)(As[0] + c0 * 8) = ga0;
  *(half8*)(As[0] + c1 * 8) = ga1;
  *(half8*)(Bs[0] + c0 * 8) = gb0;
  *(half8*)(Bs[0] + c1 * 8) = gb1;
  ga0 = *(const half8*)(pA0 + 32);
  ga1 = *(const half8*)(pA1 + 32);
  gb0 = *(const half8*)(pB0 + 32);
  gb1 = *(const half8*)(pB1 + 32);
  lds_barrier();

  #pragma unroll
  for (int i = 0; i < P1_ITERS; ++i) {
    const int cur = i & 1, nxt = cur ^ 1;
    half8 a[4], b[4];
    #pragma unroll
    for (int f = 0; f < 4; ++f) {
      a[f] = *(const half8*)(As[cur] + (((wm >> 4) + f) * 64 + lane) * 8);
      b[f] = *(const half8*)(Bs[cur] + (((wn >> 4) + f) * 64 + lane) * 8);
    }
    if (i + 1 < P1_ITERS) {
      *(half8*)(As[nxt] + c0 * 8) = ga0;
      *(half8*)(As[nxt] + c1 * 8) = ga1;
      *(half8*)(Bs[nxt] + c0 * 8) = gb0;
      *(half8*)(Bs[nxt] + c1 * 8) = gb1;
    }
    if (i + 2 < P1_ITERS) {
      int ko = (i + 2) * 32;
      ga0 = *(const half8*)(pA0 + ko);
      ga1 = *(const half8*)(pA1 + ko);
      gb0 = *(const half8*)(pB0 + ko);
      gb1 = *(const half8*)(pB1 + ko);
    }
    #pragma unroll
    for (int mf = 0; mf < 4; ++mf)
      #pragma unroll
      for (int nf = 0; nf < 4; ++nf)
        acc[mf][nf] = __builtin_amdgcn_mfma_f32_16x16x32_f16(
            a[mf], b[nf], acc[mf][nf], 0, 0, 0);
    if (i + 1 < P1_ITERS) lds_barrier();
  }

  const int col = lane & 15, qr = (lane >> 4) * 4;
  #pragma unroll
  for (int nf = 0; nf < 4; ++nf) {
    int n = n0 + wn + nf * 16 + col;
    if (n >= N3) continue;
    float bv = bias[n];
    #pragma unroll
    for (int mf = 0; mf < 4; ++mf)
      #pragma unroll
      for (int r = 0; r < 4; ++r)
        C[(size_t)(m0 + wm + mf * 16 + qr + r) * N3 + n] =
            (half_t)(acc[mf][nf][r] + bv);
  }
}

// ---- Phase 2: ONE kernel per GRU step, fully block-local. ----
// Block g (of 150) owns 16 hidden units j in [16g, 16g+16). It computes the
// FULL K=2400 dot products for all three gate planes via three B pointers
// into the planar Wf (rows 16g+., 2400+16g+., 4800+16g+.). After the MFMA
// loop each lane holds complete (Gr, Gi, Gn) for its (batch, unit) pairs in
// registers -> gate math is a pure per-lane epilogue. No split-K, no Gp
// round-trip (was 36.8 MB/step), no atomics/fences; the only cross-step
// coherence is the kernel boundary (proven by the round-0 baseline).
// 4 waves stack the batch dim: wave-tile 32(b) x 48(3 planes x 16 units).
// 1 block/CU, 1 wave/SIMD -> latency hiding is pure ILP: depth-5 rings for
// both A and B (25 loads in flight).
__global__ __launch_bounds__(256, 1) void gemm_gate(
    const half_t* __restrict__ Ah,    // hh_old [128 x 2400]
    const half_t* __restrict__ Wf,    // [7200 x 2400] planar r,i,n
    const half_t* __restrict__ gx,    // [6144 x 7200]
    const float* __restrict__ hold,   // h_old  [128 x 2400] fp32
    float* __restrict__ hnew,
    half_t* __restrict__ hhnew,
    const int* __restrict__ lengths,
    float* __restrict__ out,
    int t)
{
  const int tid  = threadIdx.x;
  const int lane = tid & 63;
  const int w    = tid >> 6;
  const int g    = blockIdx.x;       // 0..149
  const int wm   = w * 32;           // wave's batch-row offset

  const int fm = lane & 15;          // frag row within 16
  const int fk = (lane >> 4) * 8;    // frag k-offset

  const half_t* pA  = Ah + (size_t)(wm + fm) * KH + fk;        // +16*KH for mf=1
  const half_t* pBr = Wf + (size_t)(g * 16 + fm) * KH + fk;
  const half_t* pBi = pBr + (size_t)H_ * KH;
  const half_t* pBn = pBr + (size_t)(2 * H_) * KH;

  floatx4 acc[2][3] = {};   // [mf][plane]; 24 VGPR

  half8 aR[RING][2];        // 40 VGPR
  half8 bR[RING][3];        // 60 VGPR
  #pragma unroll
  for (int d = 0; d < RING; ++d) {
    aR[d][0] = *(const half8*)(pA + d * 32);
    aR[d][1] = *(const half8*)(pA + 16 * KH + d * 32);
    bR[d][0] = *(const half8*)(pBr + d * 32);
    bR[d][1] = *(const half8*)(pBi + d * 32);
    bR[d][2] = *(const half8*)(pBn + d * 32);
  }

  #pragma unroll 15
  for (int i = 0; i < P2_ITERS; ++i) {
    const int s = i % RING;
    half8 a0 = aR[s][0], a1 = aR[s][1];
    half8 br = bR[s][0], bi = bR[s][1], bn = bR[s][2];
    if (i + RING < P2_ITERS) {
      const int ko = (i + RING) * 32;
      aR[s][0] = *(const half8*)(pA + ko);
      aR[s][1] = *(const half8*)(pA + 16 * KH + ko);
      bR[s][0] = *(const half8*)(pBr + ko);
      bR[s][1] = *(const half8*)(pBi + ko);
      bR[s][2] = *(const half8*)(pBn + ko);
    }
    acc[0][0] = __builtin_amdgcn_mfma_f32_16x16x32_f16(a0, br, acc[0][0], 0, 0, 0);
    acc[1][0] = __builtin_amdgcn_mfma_f32_16x16x32_f16(a1, br, acc[1][0], 0, 0, 0);
    acc[0][1] = __builtin_amdgcn_mfma_f32_16x16x32_f16(a0, bi, acc[0][1], 0, 0, 0);
    acc[1][1] = __builtin_amdgcn_mfma_f32_16x16x32_f16(a1, bi, acc[1][1], 0, 0, 0);
    acc[0][2] = __builtin_amdgcn_mfma_f32_16x16x32_f16(a0, bn, acc[0][2], 0, 0, 0);
    acc[1][2] = __builtin_amdgcn_mfma_f32_16x16x32_f16(a1, bn, acc[1][2], 0, 0, 0);
  }

  // Per-lane gate epilogue. C-layout (verified in baseline): col = lane&15
  // (hidden unit within the 16-group), row = (lane>>4)*4 + reg (batch).
  const int j  = g * 16 + (lane & 15);
  const int qr = (lane >> 4) * 4;
  #pragma unroll
  for (int mf = 0; mf < 2; ++mf) {
    #pragma unroll
    for (int r = 0; r < 4; ++r) {
      const int b = wm + mf * 16 + qr + r;
      const size_t rx = ((size_t)b * S_ + t) * N3 + j;
      const float xr = (float)gx[rx];
      const float xi = (float)gx[rx + H_];
      const float xn = (float)gx[rx + 2 * H_];
      const float ho = hold[(size_t)b * H_ + j];
      const float rg = 1.f / (1.f + __expf(-(xr + acc[mf][0][r])));
      const float ig = 1.f / (1.f + __expf(-(xi + acc[mf][1][r])));
      const float nn = tanhf(xn + rg * acc[mf][2][r]);
      const float hv = (1.f - ig) * nn + ig * ho;
      hnew[(size_t)b * H_ + j]  = hv;
      hhnew[(size_t)b * H_ + j] = (half_t)hv;
      int lc = lengths[b] - 1;
      lc = lc < 0 ? 0 : (lc > S_ - 1 ? S_ - 1 : lc);
      if (t == lc) out[(size_t)b * H_ + j] = hv;
    }
  }
}

extern "C" void kernel_launch(void* const* d_in, const int* in_sizes, int n_in,
                              void* d_out, int out_size, void* d_ws, size_t ws_size,
                              hipStream_t stream)
{
  const int*   tokens  = (const int*)d_in[0];
  const int*   lengths = (const int*)d_in[1];
  const float* emb = (const float*)d_in[2];
  const float* Wir = (const float*)d_in[3];
  const float* Wii = (const float*)d_in[4];
  const float* Win = (const float*)d_in[5];
  const float* bir = (const float*)d_in[6];
  const float* bii = (const float*)d_in[7];
  const float* bin = (const float*)d_in[8];
  const float* Whr = (const float*)d_in[9];
  const float* Whi = (const float*)d_in[10];
  const float* Whn = (const float*)d_in[11];
  float* out = (float*)d_out;

  char* ws = (char*)d_ws;
  size_t off = 0;
  auto alloc = [&](size_t bytes) {
    void* p = ws + off;
    off = (off + bytes + 255) & ~(size_t)255;
    return p;
  };
  half_t* xb   = (half_t*)alloc((size_t)(B_ * S_) * EP * 2);   //  7.9 MB
  half_t* Wi   = (half_t*)alloc((size_t)N3 * EP * 2);          //  9.2 MB
  half_t* Wf   = (half_t*)alloc((size_t)N3 * KH * 2);          // 34.6 MB
  float*  bias = (float*)alloc((size_t)N3 * 4);
  half_t* gx   = (half_t*)alloc((size_t)(B_ * S_) * N3 * 2);   // 88.5 MB
  float*  h0   = (float*)alloc((size_t)B_ * H_ * 4);           // ping-pong h
  float*  h1   = (float*)alloc((size_t)B_ * H_ * 4);
  half_t* hh0  = (half_t*)alloc((size_t)B_ * H_ * 2);
  half_t* hh1  = (half_t*)alloc((size_t)B_ * H_ * 2);

  gather_cast_x<<<(B_ * S_ * EP) / 256, 256, 0, stream>>>(tokens, emb, xb);
  convert_wi<<<(N3 * EP) / 256, 256, 0, stream>>>(Wir, Wii, Win, bir, bii, bin, Wi, bias);
  convert_wh<<<(N3 * KH) / 256, 256, 0, stream>>>(Whr, Whi, Whn, Wf);
  init_h<<<(B_ * H_) / 256, 256, 0, stream>>>(h0, hh0);

  // Phase 1: gates_x = fp16( x @ W_i^T + b )   [6144 x 7200]
  gemm_x<<<dim3(48, 57), 256, 0, stream>>>(xb, Wi, gx, bias);

  // Phase 2: 48 GRU steps, ONE block-local fused dispatch each
  for (int t = 0; t < S_; ++t) {
    const half_t* hi = (t & 1) ? hh1 : hh0;
    half_t*       hw = (t & 1) ? hh0 : hh1;
    const float*  ho = (t & 1) ? h1  : h0;
    float*        hn = (t & 1) ? h0  : h1;
    gemm_gate<<<dim3(GBLK), 256, 0, stream>>>(
        hi, Wf, gx, ho, hn, hw, lengths, out, t);
  }
}

// Round 5
// 1778.581 us; speedup vs baseline: 2.8029x; 1.2196x over previous
//
#include <hip/hip_runtime.h>
#include <stdint.h>
#include <stddef.h>

// Problem dims
#define B_  128
#define S_  48
#define E_  620
#define EP  640    // E padded to multiple of 32 (zeros)
#define H_  2400
#define N3  7200   // 3*H (r,i,n concatenated)
#define KH  2400
#define P1_ITERS 20  // phase-1 K = 640 = 20 x 32
#define P2_ITERS 75  // phase-2 K = 2400 = 75 x 32 (full K, no split)
#define RING 5       // ring depth for A and B (75 % 5 == 0)
#define GBLK 150     // H_/16 hidden-unit groups = grid of phase 2
// Packed-chunk geometry (halves): one (g,kt,plane) chunk = 16 rows x 32 k
#define WCHUNK 512           // halves per plane-chunk (1024 B)
#define WITER  (3 * WCHUNK)  // halves per k-iter per block (3 planes)
#define WBLK   (P2_ITERS * WITER)  // halves per block's full weight stream
#define ACHUNK (B_ * 32)     // halves per k-iter of packed A (128 rows x 32 k)

typedef _Float16 half_t;
typedef __attribute__((ext_vector_type(8))) _Float16 half8;
typedef __attribute__((ext_vector_type(4))) float    floatx4;

// Workgroup barrier that waits ONLY on LDS ops; in-flight global loads keep
// flying. 0xC07F = vmcnt(63) expcnt(7) lgkmcnt(0).  (phase-1 only)
__device__ __forceinline__ void lds_barrier() {
  __builtin_amdgcn_sched_barrier(0);
  __builtin_amdgcn_s_waitcnt(0xC07F);
  __builtin_amdgcn_s_barrier();
  __builtin_amdgcn_sched_barrier(0);
}

// ---- x = fp16(emb[tokens]), padded [6144, 640] ----
__global__ void gather_cast_x(const int* __restrict__ tokens,
                              const float* __restrict__ emb,
                              half_t* __restrict__ xb) {
  int idx = blockIdx.x * 256 + threadIdx.x;       // over 6144*EP
  int m = idx / EP, c = idx - m * EP;
  float v = 0.f;
  if (c < E_) v = emb[(size_t)tokens[m] * E_ + c];
  xb[idx] = (half_t)v;
}

// ---- W_i = fp16 concat(W_ir,W_ii,W_in) [7200, 640]; bias concat [7200] ----
__global__ void convert_wi(const float* __restrict__ Wir, const float* __restrict__ Wii,
                           const float* __restrict__ Win,
                           const float* __restrict__ bir, const float* __restrict__ bii,
                           const float* __restrict__ bin,
                           half_t* __restrict__ Wi, float* __restrict__ bias) {
  int idx = blockIdx.x * 256 + threadIdx.x;       // over N3*EP
  int r = idx / EP, c = idx - r * EP;
  const float* W = (r < H_) ? Wir : (r < 2*H_ ? Wii : Win);
  int rr = (r < H_) ? r : (r < 2*H_ ? r - H_ : r - 2*H_);
  float v = (c < E_) ? W[(size_t)rr * E_ + c] : 0.f;
  Wi[idx] = (half_t)v;
  if (c == 0) {
    const float* bb = (r < H_) ? bir : (r < 2*H_ ? bii : bin);
    bias[r] = bb[rr];
  }
}

// ---- Wp = fp16 PACKED recurrent weights ----
// Layout: Wp[g][kt][plane][fm(16)][ksub(32)], g=unit-group (150), kt=k-tile
// (75), plane=r/i/n. One (g,kt,plane) chunk = 1024 B; a wave's MFMA B-frag
// (lane l: row l&15, k (l>>4)*8..+8) reads the chunk as 64 lanes x 16 B =
// fully contiguous 1024 B -> 8 cache lines/instr instead of 16 scattered
// (the round-4 TA bottleneck). Block g's whole stream = contiguous 230 KB.
__global__ void convert_wh(const float* __restrict__ Whr, const float* __restrict__ Whi,
                           const float* __restrict__ Whn, half_t* __restrict__ Wp) {
  int idx = blockIdx.x * 256 + threadIdx.x;       // over N3*KH
  int r3 = idx / KH, c = idx - r3 * KH;
  const float* W = (r3 < H_) ? Whr : (r3 < 2*H_ ? Whi : Whn);
  int p  = (r3 < H_) ? 0 : (r3 < 2*H_ ? 1 : 2);
  int rr = r3 - p * H_;
  int g = rr >> 4, fm = rr & 15;
  int kt = c >> 5, ksub = c & 31;
  size_t dst = ((size_t)g * WBLK) + (size_t)kt * WITER + p * WCHUNK + fm * 32 + ksub;
  Wp[dst] = (half_t)W[(size_t)rr * KH + c];
}

__global__ void init_h(float* __restrict__ h, half_t* __restrict__ Ap) {
  int idx = blockIdx.x * 256 + threadIdx.x;       // over B_*H_
  h[idx] = 0.f;
  Ap[idx] = (half_t)0.f;
}

// ---- Phase 1: gx = fp16( xb @ Wi^T + bias )  [6144 x 7200], K=640 ----
// (r5/r6 structure: 128x128 tile, frag-major LDS dbuf, lgkm-only barrier.)
__global__ __launch_bounds__(256, 2) void gemm_x(
    const half_t* __restrict__ A,   // xb [6144 x 640]
    const half_t* __restrict__ Bm,  // Wi [7200 x 640]
    half_t* __restrict__ C,         // gx [6144 x 7200]
    const float* __restrict__ bias)
{
  __shared__ half_t As[2][4096];
  __shared__ half_t Bs[2][4096];

  const int tid = threadIdx.x;
  const int lane = tid & 63;
  const int w = tid >> 6;
  const int m0 = blockIdx.x * 128;
  const int n0 = blockIdx.y * 128;
  const int wm = (w >> 1) * 64, wn = (w & 1) * 64;

  const int c0 = tid, c1 = tid + 256;
  const int rA0 = m0 + (c0 >> 6) * 16 + (c0 & 15), q0 = ((c0 >> 4) & 3) * 8;
  const int rA1 = m0 + (c1 >> 6) * 16 + (c1 & 15), q1 = ((c1 >> 4) & 3) * 8;
  int rB0 = n0 + (c0 >> 6) * 16 + (c0 & 15); if (rB0 >= N3) rB0 = N3 - 1;
  int rB1 = n0 + (c1 >> 6) * 16 + (c1 & 15); if (rB1 >= N3) rB1 = N3 - 1;
  const half_t* pA0 = A  + (size_t)rA0 * EP + q0;
  const half_t* pA1 = A  + (size_t)rA1 * EP + q1;
  const half_t* pB0 = Bm + (size_t)rB0 * EP + q0;
  const half_t* pB1 = Bm + (size_t)rB1 * EP + q1;

  floatx4 acc[4][4] = {};

  half8 ga0 = *(const half8*)(pA0);
  half8 ga1 = *(const half8*)(pA1);
  half8 gb0 = *(const half8*)(pB0);
  half8 gb1 = *(const half8*)(pB1);
  *(half8*)(As[0] + c0 * 8) = ga0;
  *(half8*)(As[0] + c1 * 8) = ga1;
  *(half8*)(Bs[0] + c0 * 8) = gb0;
  *(half8*)(Bs[0] + c1 * 8) = gb1;
  ga0 = *(const half8*)(pA0 + 32);
  ga1 = *(const half8*)(pA1 + 32);
  gb0 = *(const half8*)(pB0 + 32);
  gb1 = *(const half8*)(pB1 + 32);
  lds_barrier();

  #pragma unroll
  for (int i = 0; i < P1_ITERS; ++i) {
    const int cur = i & 1, nxt = cur ^ 1;
    half8 a[4], b[4];
    #pragma unroll
    for (int f = 0; f < 4; ++f) {
      a[f] = *(const half8*)(As[cur] + (((wm >> 4) + f) * 64 + lane) * 8);
      b[f] = *(const half8*)(Bs[cur] + (((wn >> 4) + f) * 64 + lane) * 8);
    }
    if (i + 1 < P1_ITERS) {
      *(half8*)(As[nxt] + c0 * 8) = ga0;
      *(half8*)(As[nxt] + c1 * 8) = ga1;
      *(half8*)(Bs[nxt] + c0 * 8) = gb0;
      *(half8*)(Bs[nxt] + c1 * 8) = gb1;
    }
    if (i + 2 < P1_ITERS) {
      int ko = (i + 2) * 32;
      ga0 = *(const half8*)(pA0 + ko);
      ga1 = *(const half8*)(pA1 + ko);
      gb0 = *(const half8*)(pB0 + ko);
      gb1 = *(const half8*)(pB1 + ko);
    }
    #pragma unroll
    for (int mf = 0; mf < 4; ++mf)
      #pragma unroll
      for (int nf = 0; nf < 4; ++nf)
        acc[mf][nf] = __builtin_amdgcn_mfma_f32_16x16x32_f16(
            a[mf], b[nf], acc[mf][nf], 0, 0, 0);
    if (i + 1 < P1_ITERS) lds_barrier();
  }

  const int col = lane & 15, qr = (lane >> 4) * 4;
  #pragma unroll
  for (int nf = 0; nf < 4; ++nf) {
    int n = n0 + wn + nf * 16 + col;
    if (n >= N3) continue;
    float bv = bias[n];
    #pragma unroll
    for (int mf = 0; mf < 4; ++mf)
      #pragma unroll
      for (int r = 0; r < 4; ++r)
        C[(size_t)(m0 + wm + mf * 16 + qr + r) * N3 + n] =
            (half_t)(acc[mf][nf][r] + bv);
  }
}

// ---- Phase 2: ONE kernel per GRU step, block-local, PACKED operands. ----
// Identical algorithm to round 4 (passed, absmax 0.0059) but every fragment
// load is now a fully-contiguous 1024-B wave access (8 lines/instr,
// sequential stream) instead of 16 scattered rows (the TA bottleneck that
// cost 42 us/step). Block g owns 16 hidden units x all 3 planes, full
// K=2400. Weight stream Wp[g] = contiguous 230 KB (L2-resident across
// steps); A = packed fp16 state Ap[kt][b][32] written by the previous
// step's epilogue. No LDS, no barriers, no atomics.
__global__ __launch_bounds__(256, 1) void gemm_gate(
    const half_t* __restrict__ Ap_old,  // packed hh [75][128][32]
    const half_t* __restrict__ Wp,      // packed weights [150][75][3][512]
    const half_t* __restrict__ gx,      // [6144 x 7200]
    const float* __restrict__ hold,     // h_old  [128 x 2400] fp32
    float* __restrict__ hnew,
    half_t* __restrict__ Ap_new,        // packed hh out
    const int* __restrict__ lengths,
    float* __restrict__ out,
    int t)
{
  const int tid  = threadIdx.x;
  const int lane = tid & 63;
  const int w    = tid >> 6;
  const int g    = blockIdx.x;       // 0..149
  const int wm   = w * 32;           // wave's batch-row offset

  const int fm = lane & 15;          // frag row within 16
  const int fk = (lane >> 4) * 8;    // frag k-offset

  // Per-lane bases; per-iter strides are compile-time constants.
  const half_t* pW = Wp + (size_t)g * WBLK + fm * 32 + fk;   // +i*WITER +p*WCHUNK
  const half_t* pA = Ap_old + (size_t)wm * 32 + fm * 32 + fk; // +i*ACHUNK +mf*512

  floatx4 acc[2][3] = {};   // [mf][plane]

  half8 aR[RING][2];
  half8 bR[RING][3];
  #pragma unroll
  for (int d = 0; d < RING; ++d) {
    aR[d][0] = *(const half8*)(pA + d * ACHUNK);
    aR[d][1] = *(const half8*)(pA + d * ACHUNK + 512);
    bR[d][0] = *(const half8*)(pW + d * WITER);
    bR[d][1] = *(const half8*)(pW + d * WITER + WCHUNK);
    bR[d][2] = *(const half8*)(pW + d * WITER + 2 * WCHUNK);
  }

  #pragma unroll 15
  for (int i = 0; i < P2_ITERS; ++i) {
    const int s = i % RING;
    half8 a0 = aR[s][0], a1 = aR[s][1];
    half8 br = bR[s][0], bi = bR[s][1], bn = bR[s][2];
    if (i + RING < P2_ITERS) {
      aR[s][0] = *(const half8*)(pA + (i + RING) * ACHUNK);
      aR[s][1] = *(const half8*)(pA + (i + RING) * ACHUNK + 512);
      bR[s][0] = *(const half8*)(pW + (i + RING) * WITER);
      bR[s][1] = *(const half8*)(pW + (i + RING) * WITER + WCHUNK);
      bR[s][2] = *(const half8*)(pW + (i + RING) * WITER + 2 * WCHUNK);
    }
    acc[0][0] = __builtin_amdgcn_mfma_f32_16x16x32_f16(a0, br, acc[0][0], 0, 0, 0);
    acc[1][0] = __builtin_amdgcn_mfma_f32_16x16x32_f16(a1, br, acc[1][0], 0, 0, 0);
    acc[0][1] = __builtin_amdgcn_mfma_f32_16x16x32_f16(a0, bi, acc[0][1], 0, 0, 0);
    acc[1][1] = __builtin_amdgcn_mfma_f32_16x16x32_f16(a1, bi, acc[1][1], 0, 0, 0);
    acc[0][2] = __builtin_amdgcn_mfma_f32_16x16x32_f16(a0, bn, acc[0][2], 0, 0, 0);
    acc[1][2] = __builtin_amdgcn_mfma_f32_16x16x32_f16(a1, bn, acc[1][2], 0, 0, 0);
  }

  // Per-lane gate epilogue. C-layout: col = lane&15 (unit), row = batch =
  // wm + mf*16 + (lane>>4)*4 + r  (verified in baseline).
  const int j  = g * 16 + (lane & 15);
  const int jb = (j >> 5) * ACHUNK + (j & 31);   // packed-A dest base
  const int qr = (lane >> 4) * 4;
  #pragma unroll
  for (int mf = 0; mf < 2; ++mf) {
    #pragma unroll
    for (int r = 0; r < 4; ++r) {
      const int b = wm + mf * 16 + qr + r;
      const size_t rx = ((size_t)b * S_ + t) * N3 + j;
      const float xr = (float)gx[rx];
      const float xi = (float)gx[rx + H_];
      const float xn = (float)gx[rx + 2 * H_];
      const float ho = hold[(size_t)b * H_ + j];
      const float rg = 1.f / (1.f + __expf(-(xr + acc[mf][0][r])));
      const float ig = 1.f / (1.f + __expf(-(xi + acc[mf][1][r])));
      const float nn = tanhf(xn + rg * acc[mf][2][r]);
      const float hv = (1.f - ig) * nn + ig * ho;
      hnew[(size_t)b * H_ + j] = hv;
      Ap_new[jb + b * 32]      = (half_t)hv;
      int lc = lengths[b] - 1;
      lc = lc < 0 ? 0 : (lc > S_ - 1 ? S_ - 1 : lc);
      if (t == lc) out[(size_t)b * H_ + j] = hv;
    }
  }
}

extern "C" void kernel_launch(void* const* d_in, const int* in_sizes, int n_in,
                              void* d_out, int out_size, void* d_ws, size_t ws_size,
                              hipStream_t stream)
{
  const int*   tokens  = (const int*)d_in[0];
  const int*   lengths = (const int*)d_in[1];
  const float* emb = (const float*)d_in[2];
  const float* Wir = (const float*)d_in[3];
  const float* Wii = (const float*)d_in[4];
  const float* Win = (const float*)d_in[5];
  const float* bir = (const float*)d_in[6];
  const float* bii = (const float*)d_in[7];
  const float* bin = (const float*)d_in[8];
  const float* Whr = (const float*)d_in[9];
  const float* Whi = (const float*)d_in[10];
  const float* Whn = (const float*)d_in[11];
  float* out = (float*)d_out;

  char* ws = (char*)d_ws;
  size_t off = 0;
  auto alloc = [&](size_t bytes) {
    void* p = ws + off;
    off = (off + bytes + 255) & ~(size_t)255;
    return p;
  };
  half_t* xb   = (half_t*)alloc((size_t)(B_ * S_) * EP * 2);   //  7.9 MB
  half_t* Wi   = (half_t*)alloc((size_t)N3 * EP * 2);          //  9.2 MB
  half_t* Wp   = (half_t*)alloc((size_t)GBLK * WBLK * 2);      // 34.6 MB packed
  float*  bias = (float*)alloc((size_t)N3 * 4);
  half_t* gx   = (half_t*)alloc((size_t)(B_ * S_) * N3 * 2);   // 88.5 MB
  float*  h0   = (float*)alloc((size_t)B_ * H_ * 4);           // ping-pong h
  float*  h1   = (float*)alloc((size_t)B_ * H_ * 4);
  half_t* Ap0  = (half_t*)alloc((size_t)B_ * H_ * 2);          // packed hh
  half_t* Ap1  = (half_t*)alloc((size_t)B_ * H_ * 2);

  gather_cast_x<<<(B_ * S_ * EP) / 256, 256, 0, stream>>>(tokens, emb, xb);
  convert_wi<<<(N3 * EP) / 256, 256, 0, stream>>>(Wir, Wii, Win, bir, bii, bin, Wi, bias);
  convert_wh<<<(N3 * KH) / 256, 256, 0, stream>>>(Whr, Whi, Whn, Wp);
  init_h<<<(B_ * H_) / 256, 256, 0, stream>>>(h0, Ap0);

  // Phase 1: gates_x = fp16( x @ W_i^T + b )   [6144 x 7200]
  gemm_x<<<dim3(48, 57), 256, 0, stream>>>(xb, Wi, gx, bias);

  // Phase 2: 48 GRU steps, one block-local fused dispatch each
  for (int t = 0; t < S_; ++t) {
    const half_t* ai = (t & 1) ? Ap1 : Ap0;
    half_t*       aw = (t & 1) ? Ap0 : Ap1;
    const float*  ho = (t & 1) ? h1  : h0;
    float*        hn = (t & 1) ? h0  : h1;
    gemm_gate<<<dim3(GBLK), 256, 0, stream>>>(
        ai, Wp, gx, ho, hn, aw, lengths, out, t);
  }
}

// Round 6
// 1658.824 us; speedup vs baseline: 3.0053x; 1.0722x over previous
//
#include <hip/hip_runtime.h>
#include <stdint.h>
#include <stddef.h>

// Problem dims
#define B_  128
#define S_  48
#define E_  620
#define EP  640    // E padded to multiple of 32 (zeros)
#define H_  2400
#define N3  7200   // 3*H (r,i,n concatenated)
#define KH  2400
#define P1_ITERS 20  // phase-1 K = 640 = 20 x 32
#define P2_ITERS 75  // phase-2 K = 2400 = 75 x 32
#define KW_ITERS 25  // per-wave k-iters (3-way K split)
#define RING 5       // ring depth (25 % 5 == 0)
#define GBLK 150     // H_/16 hidden-unit groups = grid of phase 2
// Packed-chunk geometry (halves): one (g,kt,plane) chunk = 16 rows x 32 k
#define WCHUNK 512           // halves per plane-chunk (1024 B)
#define WITER  (3 * WCHUNK)  // halves per k-iter per block (3 planes)
#define WBLK   (P2_ITERS * WITER)  // halves per block's full weight stream
#define ACHUNK (B_ * 32)     // halves per k-iter of packed A (128 rows x 32 k)

typedef _Float16 half_t;
typedef __attribute__((ext_vector_type(8))) _Float16 half8;
typedef __attribute__((ext_vector_type(4))) float    floatx4;

// Workgroup barrier that waits ONLY on LDS ops; in-flight global loads keep
// flying. 0xC07F = vmcnt(63) expcnt(7) lgkmcnt(0).  (phase-1 only)
__device__ __forceinline__ void lds_barrier() {
  __builtin_amdgcn_sched_barrier(0);
  __builtin_amdgcn_s_waitcnt(0xC07F);
  __builtin_amdgcn_s_barrier();
  __builtin_amdgcn_sched_barrier(0);
}

// ---- x = fp16(emb[tokens]), padded [6144, 640] ----
__global__ void gather_cast_x(const int* __restrict__ tokens,
                              const float* __restrict__ emb,
                              half_t* __restrict__ xb) {
  int idx = blockIdx.x * 256 + threadIdx.x;       // over 6144*EP
  int m = idx / EP, c = idx - m * EP;
  float v = 0.f;
  if (c < E_) v = emb[(size_t)tokens[m] * E_ + c];
  xb[idx] = (half_t)v;
}

// ---- W_i = fp16 concat(W_ir,W_ii,W_in) [7200, 640]; bias concat [7200] ----
__global__ void convert_wi(const float* __restrict__ Wir, const float* __restrict__ Wii,
                           const float* __restrict__ Win,
                           const float* __restrict__ bir, const float* __restrict__ bii,
                           const float* __restrict__ bin,
                           half_t* __restrict__ Wi, float* __restrict__ bias) {
  int idx = blockIdx.x * 256 + threadIdx.x;       // over N3*EP
  int r = idx / EP, c = idx - r * EP;
  const float* W = (r < H_) ? Wir : (r < 2*H_ ? Wii : Win);
  int rr = (r < H_) ? r : (r < 2*H_ ? r - H_ : r - 2*H_);
  float v = (c < E_) ? W[(size_t)rr * E_ + c] : 0.f;
  Wi[idx] = (half_t)v;
  if (c == 0) {
    const float* bb = (r < H_) ? bir : (r < 2*H_ ? bii : bin);
    bias[r] = bb[rr];
  }
}

// ---- Wp = fp16 PACKED recurrent weights ----
// Layout: Wp[g][kt][plane][fm(16)][ksub(32)]; one chunk = 1024 B = exactly
// one wave's contiguous MFMA B-frag load (the round-4->5 TA fix).
__global__ void convert_wh(const float* __restrict__ Whr, const float* __restrict__ Whi,
                           const float* __restrict__ Whn, half_t* __restrict__ Wp) {
  int idx = blockIdx.x * 256 + threadIdx.x;       // over N3*KH
  int r3 = idx / KH, c = idx - r3 * KH;
  const float* W = (r3 < H_) ? Whr : (r3 < 2*H_ ? Whi : Whn);
  int p  = (r3 < H_) ? 0 : (r3 < 2*H_ ? 1 : 2);
  int rr = r3 - p * H_;
  int g = rr >> 4, fm = rr & 15;
  int kt = c >> 5, ksub = c & 31;
  size_t dst = ((size_t)g * WBLK) + (size_t)kt * WITER + p * WCHUNK + fm * 32 + ksub;
  Wp[dst] = (half_t)W[(size_t)rr * KH + c];
}

__global__ void init_h(float* __restrict__ h, half_t* __restrict__ Ap) {
  int idx = blockIdx.x * 256 + threadIdx.x;       // over B_*H_
  h[idx] = 0.f;
  Ap[idx] = (half_t)0.f;
}

// ---- Phase 1: gx = fp16( xb @ Wi^T + bias )  [6144 x 7200], K=640 ----
// (r5/r6 structure: 128x128 tile, frag-major LDS dbuf, lgkm-only barrier.)
__global__ __launch_bounds__(256, 2) void gemm_x(
    const half_t* __restrict__ A,   // xb [6144 x 640]
    const half_t* __restrict__ Bm,  // Wi [7200 x 640]
    half_t* __restrict__ C,         // gx [6144 x 7200]
    const float* __restrict__ bias)
{
  __shared__ half_t As[2][4096];
  __shared__ half_t Bs[2][4096];

  const int tid = threadIdx.x;
  const int lane = tid & 63;
  const int w = tid >> 6;
  const int m0 = blockIdx.x * 128;
  const int n0 = blockIdx.y * 128;
  const int wm = (w >> 1) * 64, wn = (w & 1) * 64;

  const int c0 = tid, c1 = tid + 256;
  const int rA0 = m0 + (c0 >> 6) * 16 + (c0 & 15), q0 = ((c0 >> 4) & 3) * 8;
  const int rA1 = m0 + (c1 >> 6) * 16 + (c1 & 15), q1 = ((c1 >> 4) & 3) * 8;
  int rB0 = n0 + (c0 >> 6) * 16 + (c0 & 15); if (rB0 >= N3) rB0 = N3 - 1;
  int rB1 = n0 + (c1 >> 6) * 16 + (c1 & 15); if (rB1 >= N3) rB1 = N3 - 1;
  const half_t* pA0 = A  + (size_t)rA0 * EP + q0;
  const half_t* pA1 = A  + (size_t)rA1 * EP + q1;
  const half_t* pB0 = Bm + (size_t)rB0 * EP + q0;
  const half_t* pB1 = Bm + (size_t)rB1 * EP + q1;

  floatx4 acc[4][4] = {};

  half8 ga0 = *(const half8*)(pA0);
  half8 ga1 = *(const half8*)(pA1);
  half8 gb0 = *(const half8*)(pB0);
  half8 gb1 = *(const half8*)(pB1);
  *(half8*)(As[0] + c0 * 8) = ga0;
  *(half8*)(As[0] + c1 * 8) = ga1;
  *(half8*)(Bs[0] + c0 * 8) = gb0;
  *(half8*)(Bs[0] + c1 * 8) = gb1;
  ga0 = *(const half8*)(pA0 + 32);
  ga1 = *(const half8*)(pA1 + 32);
  gb0 = *(const half8*)(pB0 + 32);
  gb1 = *(const half8*)(pB1 + 32);
  lds_barrier();

  #pragma unroll
  for (int i = 0; i < P1_ITERS; ++i) {
    const int cur = i & 1, nxt = cur ^ 1;
    half8 a[4], b[4];
    #pragma unroll
    for (int f = 0; f < 4; ++f) {
      a[f] = *(const half8*)(As[cur] + (((wm >> 4) + f) * 64 + lane) * 8);
      b[f] = *(const half8*)(Bs[cur] + (((wn >> 4) + f) * 64 + lane) * 8);
    }
    if (i + 1 < P1_ITERS) {
      *(half8*)(As[nxt] + c0 * 8) = ga0;
      *(half8*)(As[nxt] + c1 * 8) = ga1;
      *(half8*)(Bs[nxt] + c0 * 8) = gb0;
      *(half8*)(Bs[nxt] + c1 * 8) = gb1;
    }
    if (i + 2 < P1_ITERS) {
      int ko = (i + 2) * 32;
      ga0 = *(const half8*)(pA0 + ko);
      ga1 = *(const half8*)(pA1 + ko);
      gb0 = *(const half8*)(pB0 + ko);
      gb1 = *(const half8*)(pB1 + ko);
    }
    #pragma unroll
    for (int mf = 0; mf < 4; ++mf)
      #pragma unroll
      for (int nf = 0; nf < 4; ++nf)
        acc[mf][nf] = __builtin_amdgcn_mfma_f32_16x16x32_f16(
            a[mf], b[nf], acc[mf][nf], 0, 0, 0);
    if (i + 1 < P1_ITERS) lds_barrier();
  }

  const int col = lane & 15, qr = (lane >> 4) * 4;
  #pragma unroll
  for (int nf = 0; nf < 4; ++nf) {
    int n = n0 + wn + nf * 16 + col;
    if (n >= N3) continue;
    float bv = bias[n];
    #pragma unroll
    for (int mf = 0; mf < 4; ++mf)
      #pragma unroll
      for (int r = 0; r < 4; ++r)
        C[(size_t)(m0 + wm + mf * 16 + qr + r) * N3 + n] =
            (half_t)(acc[mf][nf][r] + bv);
  }
}

// ---- Phase 2: one kernel/step, block-local, packed operands, 12 waves. ----
// Round-5 structure (passed, parity) + the TLP fix: 768 threads = 12 waves =
// (kw in {0,1,2}) x (mw in {0..3}). Wave (kw,mw) computes 25 of the 75
// k-iters for batch stripe 32*mw -> 3 waves/SIMD (was 1): vmcnt stalls on
// one wave are covered by the other two. K-partitioning adds ZERO global
// traffic (each A/B element still read once per block). kw=1,2 dump fp32
// partials to LDS ([kws][mw][j][lane]: lane-stride 16 B, conflict-free);
// one barrier; kw=0 sums and runs the per-lane gate epilogue (fast tanh
// via __expf; exact at saturation).
__global__ __launch_bounds__(768, 3) void gemm_gate(
    const half_t* __restrict__ Ap_old,  // packed hh [75][128][32]
    const half_t* __restrict__ Wp,      // packed weights [150][75][3][512]
    const half_t* __restrict__ gx,      // [6144 x 7200]
    const float* __restrict__ hold,     // h_old  [128 x 2400] fp32
    float* __restrict__ hnew,
    half_t* __restrict__ Ap_new,        // packed hh out
    const int* __restrict__ lengths,
    float* __restrict__ out,
    int t)
{
  __shared__ floatx4 red[2][4][6][64];   // 48 KB partials (kw=1,2)

  const int tid  = threadIdx.x;
  const int lane = tid & 63;
  const int w    = tid >> 6;        // 0..11
  const int mw   = w & 3;           // batch stripe
  const int kw   = w >> 2;          // k-slice 0..2
  const int g    = blockIdx.x;      // 0..149
  const int wm   = mw * 32;

  const int fm = lane & 15;         // frag row within 16
  const int fk = (lane >> 4) * 8;   // frag k-offset

  const half_t* pW = Wp + (size_t)g * WBLK + (size_t)kw * KW_ITERS * WITER
                        + fm * 32 + fk;
  const half_t* pA = Ap_old + (size_t)kw * KW_ITERS * ACHUNK
                            + (wm + fm) * 32 + fk;

  floatx4 acc[2][3] = {};   // [mf][plane]

  half8 aR[RING][2];
  half8 bR[RING][3];
  #pragma unroll
  for (int d = 0; d < RING; ++d) {
    aR[d][0] = *(const half8*)(pA + d * ACHUNK);
    aR[d][1] = *(const half8*)(pA + d * ACHUNK + 512);
    bR[d][0] = *(const half8*)(pW + d * WITER);
    bR[d][1] = *(const half8*)(pW + d * WITER + WCHUNK);
    bR[d][2] = *(const half8*)(pW + d * WITER + 2 * WCHUNK);
  }

  #pragma unroll
  for (int i = 0; i < KW_ITERS; ++i) {
    const int s = i % RING;
    half8 a0 = aR[s][0], a1 = aR[s][1];
    half8 br = bR[s][0], bi = bR[s][1], bn = bR[s][2];
    if (i + RING < KW_ITERS) {
      aR[s][0] = *(const half8*)(pA + (i + RING) * ACHUNK);
      aR[s][1] = *(const half8*)(pA + (i + RING) * ACHUNK + 512);
      bR[s][0] = *(const half8*)(pW + (i + RING) * WITER);
      bR[s][1] = *(const half8*)(pW + (i + RING) * WITER + WCHUNK);
      bR[s][2] = *(const half8*)(pW + (i + RING) * WITER + 2 * WCHUNK);
    }
    acc[0][0] = __builtin_amdgcn_mfma_f32_16x16x32_f16(a0, br, acc[0][0], 0, 0, 0);
    acc[1][0] = __builtin_amdgcn_mfma_f32_16x16x32_f16(a1, br, acc[1][0], 0, 0, 0);
    acc[0][1] = __builtin_amdgcn_mfma_f32_16x16x32_f16(a0, bi, acc[0][1], 0, 0, 0);
    acc[1][1] = __builtin_amdgcn_mfma_f32_16x16x32_f16(a1, bi, acc[1][1], 0, 0, 0);
    acc[0][2] = __builtin_amdgcn_mfma_f32_16x16x32_f16(a0, bn, acc[0][2], 0, 0, 0);
    acc[1][2] = __builtin_amdgcn_mfma_f32_16x16x32_f16(a1, bn, acc[1][2], 0, 0, 0);
  }

  // K-split reduction: kw=1,2 publish partials, kw=0 sums.
  if (kw != 0) {
    #pragma unroll
    for (int mf = 0; mf < 2; ++mf)
      #pragma unroll
      for (int p = 0; p < 3; ++p)
        red[kw - 1][mw][mf * 3 + p][lane] = acc[mf][p];
  }
  __syncthreads();
  if (kw != 0) return;

  #pragma unroll
  for (int mf = 0; mf < 2; ++mf)
    #pragma unroll
    for (int p = 0; p < 3; ++p)
      acc[mf][p] += red[0][mw][mf * 3 + p][lane] + red[1][mw][mf * 3 + p][lane];

  // Per-lane gate epilogue. C-layout: col = lane&15 (unit),
  // row = batch = wm + mf*16 + (lane>>4)*4 + r  (verified in baseline).
  const int j  = g * 16 + (lane & 15);
  const int jb = (j >> 5) * ACHUNK + (j & 31);   // packed-A dest base
  const int qr = (lane >> 4) * 4;
  #pragma unroll
  for (int mf = 0; mf < 2; ++mf) {
    #pragma unroll
    for (int r = 0; r < 4; ++r) {
      const int b = wm + mf * 16 + qr + r;
      const size_t rx = ((size_t)b * S_ + t) * N3 + j;
      const float xr = (float)gx[rx];
      const float xi = (float)gx[rx + H_];
      const float xn = (float)gx[rx + 2 * H_];
      const float ho = hold[(size_t)b * H_ + j];
      const float rg = 1.f / (1.f + __expf(-(xr + acc[mf][0][r])));
      const float ig = 1.f / (1.f + __expf(-(xi + acc[mf][1][r])));
      const float ta = xn + rg * acc[mf][2][r];
      const float nn = 1.f - 2.f / (1.f + __expf(2.f * ta));  // tanh(ta)
      const float hv = (1.f - ig) * nn + ig * ho;
      hnew[(size_t)b * H_ + j] = hv;
      Ap_new[jb + b * 32]      = (half_t)hv;
      int lc = lengths[b] - 1;
      lc = lc < 0 ? 0 : (lc > S_ - 1 ? S_ - 1 : lc);
      if (t == lc) out[(size_t)b * H_ + j] = hv;
    }
  }
}

extern "C" void kernel_launch(void* const* d_in, const int* in_sizes, int n_in,
                              void* d_out, int out_size, void* d_ws, size_t ws_size,
                              hipStream_t stream)
{
  const int*   tokens  = (const int*)d_in[0];
  const int*   lengths = (const int*)d_in[1];
  const float* emb = (const float*)d_in[2];
  const float* Wir = (const float*)d_in[3];
  const float* Wii = (const float*)d_in[4];
  const float* Win = (const float*)d_in[5];
  const float* bir = (const float*)d_in[6];
  const float* bii = (const float*)d_in[7];
  const float* bin = (const float*)d_in[8];
  const float* Whr = (const float*)d_in[9];
  const float* Whi = (const float*)d_in[10];
  const float* Whn = (const float*)d_in[11];
  float* out = (float*)d_out;

  char* ws = (char*)d_ws;
  size_t off = 0;
  auto alloc = [&](size_t bytes) {
    void* p = ws + off;
    off = (off + bytes + 255) & ~(size_t)255;
    return p;
  };
  half_t* xb   = (half_t*)alloc((size_t)(B_ * S_) * EP * 2);   //  7.9 MB
  half_t* Wi   = (half_t*)alloc((size_t)N3 * EP * 2);          //  9.2 MB
  half_t* Wp   = (half_t*)alloc((size_t)GBLK * WBLK * 2);      // 34.6 MB packed
  float*  bias = (float*)alloc((size_t)N3 * 4);
  half_t* gx   = (half_t*)alloc((size_t)(B_ * S_) * N3 * 2);   // 88.5 MB
  float*  h0   = (float*)alloc((size_t)B_ * H_ * 4);           // ping-pong h
  float*  h1   = (float*)alloc((size_t)B_ * H_ * 4);
  half_t* Ap0  = (half_t*)alloc((size_t)B_ * H_ * 2);          // packed hh
  half_t* Ap1  = (half_t*)alloc((size_t)B_ * H_ * 2);

  gather_cast_x<<<(B_ * S_ * EP) / 256, 256, 0, stream>>>(tokens, emb, xb);
  convert_wi<<<(N3 * EP) / 256, 256, 0, stream>>>(Wir, Wii, Win, bir, bii, bin, Wi, bias);
  convert_wh<<<(N3 * KH) / 256, 256, 0, stream>>>(Whr, Whi, Whn, Wp);
  init_h<<<(B_ * H_) / 256, 256, 0, stream>>>(h0, Ap0);

  // Phase 1: gates_x = fp16( x @ W_i^T + b )   [6144 x 7200]
  gemm_x<<<dim3(48, 57), 256, 0, stream>>>(xb, Wi, gx, bias);

  // Phase 2: 48 GRU steps, one block-local fused dispatch each (12 waves)
  for (int t = 0; t < S_; ++t) {
    const half_t* ai = (t & 1) ? Ap1 : Ap0;
    half_t*       aw = (t & 1) ? Ap0 : Ap1;
    const float*  ho = (t & 1) ? h1  : h0;
    float*        hn = (t & 1) ? h0  : h1;
    gemm_gate<<<dim3(GBLK), 768, 0, stream>>>(
        ai, Wp, gx, ho, hn, aw, lengths, out, t);
  }
}